// Round 1
// baseline (2844.684 us; speedup 1.0000x reference)
//
#include <hip/hip_runtime.h>
#include <hip/hip_fp16.h>

// CRF mean-field iteration, NHWC throughout (no transposes).
// Per iter: out = x + sw * blurW(blurH(softmax_C(xc)))   [center taps zeroed]
// 5 iterations, fused one-kernel-per-iteration, intermediates in LDS only.

#define BB    16
#define Himg  384
#define Wimg  384
#define CC    21
#define TH    16
#define TW    16
#define RR    4
#define PH    (TH + 2*RR)        // 24
#define PW    (TW + 2*RR)        // 24
#define ROWF  (PW * CC)          // 504 floats per staged halo row
#define NPIX  (PH * PW)          // 576
#define HALO_ELEMS (PH * ROWF)   // 12096
#define OUT_ELEMS  (TH * TW * CC) // 5376

__global__ __launch_bounds__(256, 2)
void crf_iter_kernel(const float* __restrict__ xin,       // current logits, NHWC
                     const float* __restrict__ unary,     // original x, NHWC
                     float* __restrict__ out,
                     const float* __restrict__ spacings,  // (B,2)
                     const float* __restrict__ inv_theta, // (2,)
                     const float* __restrict__ sw_ptr)    // (1,)
{
    __shared__ float  bufA[HALO_ELEMS];        // raw xc -> p -> staged output (reused)
    __shared__ __half bufB[TH * ROWF];         // vertical blur result (<=0.55, fp16 ok)

    const int tid = threadIdx.x;
    const int b   = blockIdx.z;
    const int h0  = blockIdx.y * TH;
    const int w0  = blockIdx.x * TW;

    // Runtime Gaussian taps (per-batch spacing, shared theta), center tap zeroed.
    const float sp_h = spacings[b * 2 + 0];
    const float sp_w = spacings[b * 2 + 1];
    const float ith  = inv_theta[0];
    const float itw  = inv_theta[1];
    const float sw   = sw_ptr[0];
    float kh[9], kw[9];
#pragma unroll
    for (int i = 0; i < 9; ++i) {
        float dh = sp_h * (float)(i - 4) * ith;
        float dw = sp_w * (float)(i - 4) * itw;
        kh[i] = (i == 4) ? 0.f : __expf(-0.5f * dh * dh);
        kw[i] = (i == 4) ? 0.f : __expf(-0.5f * dw * dw);
    }

    // ---- Phase 1: stage raw xc halo tile (coalesced row-wise f32 loads) ----
    {
        const int base_b = b * Himg;
        for (int idx = tid; idx < HALO_ELEMS; idx += 256) {
            int r  = idx / ROWF;           // halo row 0..23
            int o  = idx - r * ROWF;       // 0..503
            int hh = h0 - RR + r;
            int wp = o / CC;               // 0..23
            int gw = w0 - RR + wp;
            if (hh >= 0 && hh < Himg && gw >= 0 && gw < Wimg) {
                int gaddr = ((base_b + hh) * Wimg + (w0 - RR)) * CC + o;
                bufA[idx] = xin[gaddr];
            }
            // else: garbage stays; phase 2 overwrites those pixels with p=0
        }
    }
    __syncthreads();

    // ---- Phase 2: per-pixel softmax over C, in place; zero-pad OOB pixels ----
    for (int p = tid; p < NPIX; p += 256) {
        int r   = p / PW;
        int cpx = p - r * PW;
        int hh  = h0 - RR + r;
        int gw  = w0 - RR + cpx;
        float* px = &bufA[p * CC];
        if (hh >= 0 && hh < Himg && gw >= 0 && gw < Wimg) {
            float v[CC];
            float m = -1e30f;
#pragma unroll
            for (int c = 0; c < CC; ++c) { v[c] = px[c]; m = fmaxf(m, v[c]); }
            float s = 0.f;
#pragma unroll
            for (int c = 0; c < CC; ++c) { v[c] = __expf(v[c] - m); s += v[c]; }
            float inv = 1.f / s;
#pragma unroll
            for (int c = 0; c < CC; ++c) px[c] = v[c] * inv;
        } else {
#pragma unroll
            for (int c = 0; c < CC; ++c) px[c] = 0.f;
        }
    }
    __syncthreads();

    // ---- Phase 3: vertical blur. One (w,c) column per task: 24 reads -> 16 outputs ----
    for (int o = tid; o < ROWF; o += 256) {
        float v[PH];
#pragma unroll
        for (int r = 0; r < PH; ++r) v[r] = bufA[r * ROWF + o];
#pragma unroll
        for (int t = 0; t < TH; ++t) {
            float acc = 0.f;
#pragma unroll
            for (int i = 0; i < 9; ++i) {
                if (i == 4) continue;      // center tap zero
                acc = fmaf(kh[i], v[t + i], acc);
            }
            bufB[t * ROWF + o] = __float2half(acc);
        }
    }
    __syncthreads();

    // ---- Phase 4: horizontal blur * sw; staged into bufA[0..OUT_ELEMS) ----
    for (int o = tid; o < TH * CC; o += 256) {   // task = (h, c)
        int h = o / CC;
        int c = o - h * CC;
        float v[PW];
#pragma unroll
        for (int wp = 0; wp < PW; ++wp) v[wp] = __half2float(bufB[h * ROWF + wp * CC + c]);
#pragma unroll
        for (int wt = 0; wt < TW; ++wt) {
            float acc = 0.f;
#pragma unroll
            for (int j = 0; j < 9; ++j) {
                if (j == 4) continue;
                acc = fmaf(kw[j], v[wt + j], acc);
            }
            bufA[(h * TW + wt) * CC + c] = sw * acc;
        }
    }
    __syncthreads();

    // ---- Phase 5: out = unary + s (coalesced read-modify-write) ----
    {
        const int gbase = ((b * Himg + h0) * Wimg + w0) * CC;
        for (int i = tid; i < OUT_ELEMS; i += 256) {
            int h   = i / (TW * CC);
            int rem = i - h * (TW * CC);
            int gaddr = gbase + h * (Wimg * CC) + rem;
            out[gaddr] = unary[gaddr] + bufA[i];
        }
    }
}

extern "C" void kernel_launch(void* const* d_in, const int* in_sizes, int n_in,
                              void* d_out, int out_size, void* d_ws, size_t ws_size,
                              hipStream_t stream) {
    const float* x         = (const float*)d_in[0];
    const float* spacings  = (const float*)d_in[1];
    const float* sw        = (const float*)d_in[2];
    const float* inv_theta = (const float*)d_in[3];
    float* out = (float*)d_out;
    float* ws  = (float*)d_ws;   // needs 198 MB: one ping-pong buffer

    dim3 grid(Wimg / TW, Himg / TH, BB);   // 24 x 24 x 16 = 9216 blocks
    dim3 block(256);

    // iter1: x->out, iter2: out->ws, iter3: ws->out, iter4: out->ws, iter5: ws->out
    crf_iter_kernel<<<grid, block, 0, stream>>>(x,   x, out, spacings, inv_theta, sw);
    crf_iter_kernel<<<grid, block, 0, stream>>>(out, x, ws,  spacings, inv_theta, sw);
    crf_iter_kernel<<<grid, block, 0, stream>>>(ws,  x, out, spacings, inv_theta, sw);
    crf_iter_kernel<<<grid, block, 0, stream>>>(out, x, ws,  spacings, inv_theta, sw);
    crf_iter_kernel<<<grid, block, 0, stream>>>(ws,  x, out, spacings, inv_theta, sw);
}

// Round 2
// 1130.727 us; speedup vs baseline: 2.5158x; 2.5158x over previous
//
#include <hip/hip_runtime.h>
#include <hip/hip_fp16.h>

// CRF mean-field, NHWC. Per iter: out = x + sw * blurW(blurH(softmax_C(xc)))
// fp16 LDS staging (40320 B -> 4 blocks/CU), float4 global I/O.

#define BB    16
#define Himg  384
#define Wimg  384
#define CC    21
#define TH    16
#define TW    16
#define RR    4
#define PH    (TH + 2*RR)          // 24
#define PW    (TW + 2*RR)          // 24
#define ROWF  (PW * CC)            // 504 elems per halo row
#define NPIX  (PH * PW)            // 576
#define OUT_ELEMS (TH * TW * CC)   // 5376
#define CHUNKS_ROW (ROWF / 4)      // 126 float4 per halo row
#define NCHUNK (PH * CHUNKS_ROW)   // 3024
#define NTOT  (BB * Himg * Wimg * CC)  // 49545216 (< 2^31)

__global__ __launch_bounds__(256, 4)
void crf_iter_kernel(const float* __restrict__ xin,
                     const float* __restrict__ unary,
                     float* __restrict__ out,
                     const float* __restrict__ spacings,
                     const float* __restrict__ inv_theta,
                     const float* __restrict__ sw_ptr)
{
    // pbuf (fp16 logits -> p, 24192 B) is dead after phase 3; its region is
    // reused as fp32 s-staging (21504 B) in phase 4/5.
    __shared__ __align__(16) unsigned char smem[40320];
    __half* pbuf = (__half*)smem;               // 12096 halves
    float*  sbuf = (float*)smem;                // 5376 floats (aliases pbuf)
    __half* tbuf = (__half*)(smem + 24192);     // 8064 halves (vertical tmp)

    const int tid = threadIdx.x;
    const int b   = blockIdx.z;
    const int h0  = blockIdx.y * TH;
    const int w0  = blockIdx.x * TW;

    const float sp_h = spacings[b * 2 + 0];
    const float sp_w = spacings[b * 2 + 1];
    const float ith  = inv_theta[0];
    const float itw  = inv_theta[1];
    const float sw   = sw_ptr[0];
    float kh[9], kw[9];
#pragma unroll
    for (int i = 0; i < 9; ++i) {
        float dh = sp_h * (float)(i - 4) * ith;
        float dw = sp_w * (float)(i - 4) * itw;
        kh[i] = (i == 4) ? 0.f : __expf(-0.5f * dh * dh);
        kw[i] = (i == 4) ? 0.f : __expf(-0.5f * dw * dw);
    }

    // ---- Phase 1: stage logits halo as fp16 via float4 loads ----
    // Row segment (504 floats) is 16B-aligned for every tile. Addresses are
    // clamped to the tensor; clamped lanes hold garbage but correspond to
    // out-of-image pixels that phase 2 overwrites with 0.
    {
        __half2* pb2 = (__half2*)pbuf;
        for (int idx = tid; idx < NCHUNK; idx += 256) {
            int r  = idx / CHUNKS_ROW;
            int q  = idx - r * CHUNKS_ROW;
            int hh = h0 - RR + r;
            if (hh >= 0 && hh < Himg) {
                int basef = ((b * Himg + hh) * Wimg + (w0 - RR)) * CC + q * 4;
                int a = basef < 0 ? 0 : (basef > NTOT - 4 ? NTOT - 4 : basef);
                float4 v = *(const float4*)(xin + a);
                __half2 lo, hi;
                lo.x = __float2half_rn(v.x); lo.y = __float2half_rn(v.y);
                hi.x = __float2half_rn(v.z); hi.y = __float2half_rn(v.w);
                pb2[idx * 2]     = lo;
                pb2[idx * 2 + 1] = hi;
            }
            // OOB rows: stale LDS; phase 2 zeroes those pixels.
        }
    }
    __syncthreads();

    // ---- Phase 2: per-pixel softmax over C in place; zero OOB pixels ----
    for (int p = tid; p < NPIX; p += 256) {
        int r   = p / PW;
        int cpx = p - r * PW;
        int hh  = h0 - RR + r;
        int gw  = w0 - RR + cpx;
        __half* px = pbuf + p * CC;
        if (hh >= 0 && hh < Himg && gw >= 0 && gw < Wimg) {
            float v[CC];
            float m = -1e30f;
#pragma unroll
            for (int c = 0; c < CC; ++c) { v[c] = __half2float(px[c]); m = fmaxf(m, v[c]); }
            float s = 0.f;
#pragma unroll
            for (int c = 0; c < CC; ++c) { v[c] = __expf(v[c] - m); s += v[c]; }
            float inv = 1.f / s;
#pragma unroll
            for (int c = 0; c < CC; ++c) px[c] = __float2half_rn(v[c] * inv);
        } else {
            const __half z = __float2half_rn(0.f);
#pragma unroll
            for (int c = 0; c < CC; ++c) px[c] = z;
        }
    }
    __syncthreads();

    // ---- Phase 3: vertical blur, half2 columns (252 tasks, one pass) ----
    if (tid < ROWF / 2) {
        const __half2* pb2 = (const __half2*)pbuf;
        __half2* tb2 = (__half2*)tbuf;
        const int o2 = tid;
        float2 v[PH];
#pragma unroll
        for (int r = 0; r < PH; ++r) v[r] = __half22float2(pb2[r * (ROWF / 2) + o2]);
#pragma unroll
        for (int t = 0; t < TH; ++t) {
            float ax = 0.f, ay = 0.f;
#pragma unroll
            for (int i = 0; i < 9; ++i) {
                if (i == 4) continue;
                ax = fmaf(kh[i], v[t + i].x, ax);
                ay = fmaf(kh[i], v[t + i].y, ay);
            }
            __half2 o; o.x = __float2half_rn(ax); o.y = __float2half_rn(ay);
            tb2[t * (ROWF / 2) + o2] = o;
        }
    }
    __syncthreads();   // tbuf ready AND pbuf region now free -> sbuf

    // ---- Phase 4: horizontal blur * sw -> fp32 s staged in sbuf ----
    for (int o = tid; o < TH * CC; o += 256) {   // 336 tasks: (h, c)
        int h = o / CC;
        int c = o - h * CC;
        float v[PW];
#pragma unroll
        for (int wp = 0; wp < PW; ++wp) v[wp] = __half2float(tbuf[h * ROWF + wp * CC + c]);
#pragma unroll
        for (int wt = 0; wt < TW; ++wt) {
            float acc = 0.f;
#pragma unroll
            for (int j = 0; j < 9; ++j) {
                if (j == 4) continue;
                acc = fmaf(kw[j], v[wt + j], acc);
            }
            sbuf[(h * TW + wt) * CC + c] = sw * acc;
        }
    }
    __syncthreads();

    // ---- Phase 5: out = unary + s, float4 RMW (1344 tasks) ----
    {
        const int gbase = ((b * Himg + h0) * Wimg + w0) * CC;
        for (int j = tid; j < OUT_ELEMS / 4; j += 256) {
            int hrow = j / (TW * CC / 4);            // 84 chunks per h-row
            int qq   = j - hrow * (TW * CC / 4);
            int g = gbase + hrow * (Wimg * CC) + qq * 4;
            float4 u = *(const float4*)(unary + g);
            float4 s = *(const float4*)(sbuf + hrow * (TW * CC) + qq * 4);
            float4 o;
            o.x = u.x + s.x; o.y = u.y + s.y; o.z = u.z + s.z; o.w = u.w + s.w;
            *(float4*)(out + g) = o;
        }
    }
}

extern "C" void kernel_launch(void* const* d_in, const int* in_sizes, int n_in,
                              void* d_out, int out_size, void* d_ws, size_t ws_size,
                              hipStream_t stream) {
    const float* x         = (const float*)d_in[0];
    const float* spacings  = (const float*)d_in[1];
    const float* sw        = (const float*)d_in[2];
    const float* inv_theta = (const float*)d_in[3];
    float* out = (float*)d_out;
    float* ws  = (float*)d_ws;

    dim3 grid(Wimg / TW, Himg / TH, BB);   // 24 x 24 x 16 = 9216 blocks
    dim3 block(256);

    crf_iter_kernel<<<grid, block, 0, stream>>>(x,   x, out, spacings, inv_theta, sw);
    crf_iter_kernel<<<grid, block, 0, stream>>>(out, x, ws,  spacings, inv_theta, sw);
    crf_iter_kernel<<<grid, block, 0, stream>>>(ws,  x, out, spacings, inv_theta, sw);
    crf_iter_kernel<<<grid, block, 0, stream>>>(out, x, ws,  spacings, inv_theta, sw);
    crf_iter_kernel<<<grid, block, 0, stream>>>(ws,  x, out, spacings, inv_theta, sw);
}